// Round 3
// baseline (391.267 us; speedup 1.0000x reference)
//
#include <hip/hip_runtime.h>

// Problem dims
#define T_LEN 8192
#define H_DIM 2048
#define K_DIM 512
#define V_DIM 512
#define O_DIM 2048
#define CHUNK 64
#define NCHUNK 128   // T_LEN / CHUNK

typedef short bf16x8 __attribute__((ext_vector_type(8)));
typedef float f32x4 __attribute__((ext_vector_type(4)));

typedef const __attribute__((address_space(1))) void* gptr1_t;
typedef __attribute__((address_space(3))) void* lptr3_t;

__device__ __forceinline__ float b2f(unsigned short u) {
    unsigned int i = ((unsigned int)u) << 16;
    float f;
    __builtin_memcpy(&f, &i, 4);
    return f;
}
__device__ __forceinline__ unsigned short f2b(float f) {
    unsigned int i;
    __builtin_memcpy(&i, &f, 4);
    unsigned int r = (i + 0x7FFFu + ((i >> 16) & 1u)) >> 16;  // RNE
    return (unsigned short)r;
}
// NaN/inf firewall
__device__ __forceinline__ float fw(float v) {
    return fminf(fmaxf(v, -1e30f), 1e30f);
}

#define BARX() asm volatile("s_barrier" ::: "memory")
#define ORDER() asm volatile("" ::: "memory")

// global_load_lds (16B) + stage-pair helpers; expand in kernels that declare
// `lds` (shared short array) and `tid`.
#define GLDS(gp, dstByte)                                                      \
    __builtin_amdgcn_global_load_lds((gptr1_t)(const void*)(gp),               \
                                     (lptr3_t)(void*)((char*)lds + (dstByte)), \
                                     16, 0, 0)
#define STAGE2(p0, p1, dstBase)                                                \
    do {                                                                       \
        GLDS(p0, (dstBase) + tid * 16);                                        \
        GLDS(p1, (dstBase) + 8192 + tid * 16);                                 \
    } while (0)

// ---------------------------------------------------------------------------
// Runtime C/D-layout probe for mfma_f32_16x16x32_bf16 (vs our load convention).
__global__ __launch_bounds__(64) void probe_k(int* __restrict__ flag) {
    __shared__ unsigned short As[16 * 32];
    __shared__ unsigned short Bs[16 * 32];
    int tid = threadIdx.x;
    for (int idx = tid; idx < 512; idx += 64) {
        int r = idx >> 5, c = idx & 31;
        float av = (c == 0) ? (float)(r + 1) : (c == 1 ? 1.0f : 0.0f);
        float bv = (c == 0) ? 1.0f : (c == 1 ? (float)(1024 * (r + 1)) : 0.0f);
        As[r * 32 + c] = f2b(av);
        Bs[r * 32 + c] = f2b(bv);
    }
    __syncthreads();
    int ln15 = tid & 15, q4 = (tid & 63) >> 4;
    bf16x8 a = *(const bf16x8*)(As + ln15 * 32 + q4 * 8);
    bf16x8 b = *(const bf16x8*)(Bs + ln15 * 32 + q4 * 8);
    f32x4 acc = {0.f, 0.f, 0.f, 0.f};
    acc = __builtin_amdgcn_mfma_f32_16x16x32_bf16(a, b, acc, 0, 0, 0);
    bool h0 = true, h1 = true;
#pragma unroll
    for (int i = 0; i < 4; i++) {
        float e0 = (float)((q4 * 4 + i + 1) + 1024 * (ln15 + 1));
        float e1 = (float)((ln15 + 1) + 1024 * (q4 * 4 + i + 1));
        h0 = h0 && (acc[i] == e0);
        h1 = h1 && (acc[i] == e1);
    }
    unsigned long long b0 = __ballot(h0 ? 1 : 0);
    unsigned long long b1 = __ballot(h1 ? 1 : 0);
    if (tid == 0) *flag = (b0 == ~0ull) ? 0 : ((b1 == ~0ull) ? 1 : 0);
}

// ---------------------------------------------------------------------------
// Merged prep: fp32->bf16 conv of hidden_state (blocks 0..8191) + 5 weight
// transposes to bf16 (blocks 8192..13311, 1024 tiles per matrix).
__global__ __launch_bounds__(256) void prep_k(const float* __restrict__ hs,
                                              unsigned short* __restrict__ hsb,
                                              const float* __restrict__ Wq,
                                              const float* __restrict__ Wk,
                                              const float* __restrict__ Wg,
                                              const float* __restrict__ Wv,
                                              const float* __restrict__ Wo,
                                              unsigned short* __restrict__ WT,
                                              unsigned short* __restrict__ WoT) {
    __shared__ unsigned short tile[32][33];
    long bid = blockIdx.x;
    int tid = threadIdx.x;
    if (bid < 8192) {
        long i = (bid * 256 + tid) * 8;
        unsigned int wd[4];
#pragma unroll
        for (int u = 0; u < 4; u++) {
            unsigned short lo = f2b(hs[i + 2 * u]);
            unsigned short hi = f2b(hs[i + 2 * u + 1]);
            wd[u] = (unsigned int)lo | ((unsigned int)hi << 16);
        }
        uint4 pk; pk.x = wd[0]; pk.y = wd[1]; pk.z = wd[2]; pk.w = wd[3];
        *(uint4*)(hsb + i) = pk;
        return;
    }
    int t = (int)(bid - 8192);
    int mat = t >> 10, tl = t & 1023;
    const float* in; unsigned short* outp; int R, C, br, bc;
    if (mat < 4) {
        in = mat == 0 ? Wq : mat == 1 ? Wk : mat == 2 ? Wg : Wv;
        outp = WT + (long)mat * 512 * H_DIM;
        R = H_DIM; C = 512; br = tl >> 4; bc = tl & 15;
    } else {
        in = Wo; outp = WoT; R = V_DIM; C = O_DIM; br = tl & 15; bc = tl >> 4;
    }
    int tc = tid & 31, tr = tid >> 5;
#pragma unroll
    for (int i = 0; i < 4; i++) {
        int r = tr + 8 * i;
        long idx = (long)(br * 32 + r) * C + bc * 32 + tc;
        tile[r][tc] = f2b(in[idx]);
    }
    __syncthreads();
#pragma unroll
    for (int i = 0; i < 4; i++) {
        int r = tr + 8 * i;
        outp[(long)(bc * 32 + r) * R + br * 32 + tc] = tile[tc][r];
    }
}

// ---------------------------------------------------------------------------
// Fused projection GEMM, 256x256 8-phase (T2+T3+T4+T5), VALU-free addressing:
//  - LDS read addr = laneBase (+buf bit15) (^ s bit6) (+ compile-time offset):
//    bit-fields disjoint, so ds_read_b128 gets an offset: immediate, ~0 VALU.
//  - staging via 8 running per-thread pointers, +128 B/tile, no wrap (tail
//    overruns land in mapped workspace regions, audited).
//  - counted prefetch: vmcnt(8) at ends of phases r0/r1/r3; every half-tile
//    has 5-6 phases of latency cover; never drains below 8 in-flight loads.
__global__ __launch_bounds__(512, 2) void proj_gemm256_k(const unsigned short* __restrict__ A,
                                                         const unsigned short* __restrict__ WT,
                                                         const float* __restrict__ bq,
                                                         const float* __restrict__ bk,
                                                         const float* __restrict__ bg,
                                                         const float* __restrict__ bv,
                                                         unsigned short* __restrict__ qb,
                                                         unsigned short* __restrict__ kb,
                                                         float* __restrict__ gb,
                                                         unsigned short* __restrict__ vT,
                                                         const int* __restrict__ flagp) {
    __shared__ short lds[65536];  // [A: 2 bufs x 32KB][B: 2 bufs x 32KB] = 128 KiB
    int fl = *flagp;
    int tid = threadIdx.x;
    int lane = tid & 63;
    int ln15 = lane & 15, q4 = lane >> 4;
    int w = tid >> 6;
    int wm = w >> 2, wn = w & 3;  // 2 x 4 wave grid; wave owns 128 rows x 64 cols
    long m0 = (long)blockIdx.x * 256, n0 = (long)blockIdx.y * 256;

    // lane-base LDS byte offsets (swizzled slot; s=0, buf=0)
    unsigned slot = ((unsigned)(q4 * 16)) ^ ((unsigned)((ln15 & 7) << 4));
    unsigned aoff0 = (unsigned)(wm * 8192 + ln15 * 128) + slot;
    unsigned boff0 = 65536u + (unsigned)(wn * 4096 + ln15 * 128) + slot;

    // staging source geometry (T2 pre-swizzled global source)
    int idx0 = tid, idx1 = 512 + tid;
    int r0_ = idx0 >> 3, r1_ = idx1 >> 3;
    int c80 = (idx0 & 7) ^ (r0_ & 7);
    int c81 = (idx1 & 7) ^ (r1_ & 7);
    int trA0 = ((r0_ >> 6) & 1) * 128 + (r0_ & 63);
    int trA1 = ((r1_ >> 6) & 1) * 128 + (r1_ & 63);
    int tcB0 = ((r0_ >> 5) & 3) * 64 + (r0_ & 31);
    int tcB1 = ((r1_ >> 5) & 3) * 64 + (r1_ & 31);
    const unsigned short* pAlo0 = A + (m0 + trA0) * (long)H_DIM + c80 * 8;
    const unsigned short* pAlo1 = A + (m0 + trA1) * (long)H_DIM + c81 * 8;
    const unsigned short* pAhi0 = pAlo0 + 64 * H_DIM;
    const unsigned short* pAhi1 = pAlo1 + 64 * H_DIM;
    const unsigned short* pBlo0 = WT + (n0 + tcB0) * (long)H_DIM + c80 * 8;
    const unsigned short* pBlo1 = WT + (n0 + tcB1) * (long)H_DIM + c81 * 8;
    const unsigned short* pBhi0 = pBlo0 + 32 * H_DIM;
    const unsigned short* pBhi1 = pBlo1 + 32 * H_DIM;

    f32x4 acc[8][4] = {};

    // prologue: tile0 full -> buf0, tile1 lo-halves -> buf1; pointers advance
    STAGE2(pAlo0, pAlo1, 0);
    STAGE2(pBlo0, pBlo1, 65536);
    ORDER();
    STAGE2(pBhi0, pBhi1, 65536 + 16384);
    STAGE2(pAhi0, pAhi1, 16384);
    ORDER();
    pAlo0 += 64; pAlo1 += 64; pBlo0 += 64; pBlo1 += 64;
    STAGE2(pAlo0, pAlo1, 32768);
    STAGE2(pBlo0, pBlo1, 65536 + 32768);
    ORDER();
    pAlo0 += 64; pAlo1 += 64; pBlo0 += 64; pBlo1 += 64;
    pAhi0 += 64; pAhi1 += 64; pBhi0 += 64; pBhi1 += 64;
    asm volatile("s_waitcnt vmcnt(8)" ::: "memory");  // tile0 lo-halves landed
    BARX();

    int cur = 0;
    const char* L = (const char*)lds;
    for (int kt = 0; kt < H_DIM; kt += 64, cur ^= 1) {
        int nxt = cur ^ 1;
        unsigned bufb = (unsigned)cur << 15;
        unsigned ab0 = aoff0 + bufb, ab1 = ab0 ^ 64u;
        unsigned bb0 = boff0 + bufb, bb1 = bb0 ^ 64u;
        bf16x8 af[4][2], blo[2][2], bhi[2][2];

        // ---- phase r0: quadrant (m-lo, n-lo); stage B-hi(t+1) ----
#pragma unroll
        for (int i = 0; i < 4; i++) {
            af[i][0] = *(const bf16x8*)(L + ab0 + i * 2048);
            af[i][1] = *(const bf16x8*)(L + ab1 + i * 2048);
        }
#pragma unroll
        for (int j = 0; j < 2; j++) {
            blo[j][0] = *(const bf16x8*)(L + bb0 + j * 2048);
            blo[j][1] = *(const bf16x8*)(L + bb1 + j * 2048);
        }
        STAGE2(pBhi0, pBhi1, 65536 + nxt * 32768 + 16384);
        BARX();
        __builtin_amdgcn_s_setprio(1);
#pragma unroll
        for (int i = 0; i < 4; i++)
#pragma unroll
            for (int j = 0; j < 2; j++) {
                acc[i][j] = __builtin_amdgcn_mfma_f32_16x16x32_bf16(af[i][0], blo[j][0], acc[i][j], 0, 0, 0);
                acc[i][j] = __builtin_amdgcn_mfma_f32_16x16x32_bf16(af[i][1], blo[j][1], acc[i][j], 0, 0, 0);
            }
        __builtin_amdgcn_s_setprio(0);
        asm volatile("s_waitcnt vmcnt(8)" ::: "memory");  // B-hi(t) landed
        BARX();

        // ---- phase r1: quadrant (m-lo, n-hi); stage A-hi(t+1) ----
#pragma unroll
        for (int j = 0; j < 2; j++) {
            bhi[j][0] = *(const bf16x8*)(L + bb0 + 16384 + j * 2048);
            bhi[j][1] = *(const bf16x8*)(L + bb1 + 16384 + j * 2048);
        }
        STAGE2(pAhi0, pAhi1, nxt * 32768 + 16384);
        BARX();
        __builtin_amdgcn_s_setprio(1);
#pragma unroll
        for (int i = 0; i < 4; i++)
#pragma unroll
            for (int j = 0; j < 2; j++) {
                acc[i][2 + j] = __builtin_amdgcn_mfma_f32_16x16x32_bf16(af[i][0], bhi[j][0], acc[i][2 + j], 0, 0, 0);
                acc[i][2 + j] = __builtin_amdgcn_mfma_f32_16x16x32_bf16(af[i][1], bhi[j][1], acc[i][2 + j], 0, 0, 0);
            }
        __builtin_amdgcn_s_setprio(0);
        asm volatile("s_waitcnt vmcnt(8)" ::: "memory");  // A-hi(t) landed
        BARX();

        // ---- phase r2: quadrant (m-hi, n-hi); stage A-lo(t+2) ----
#pragma unroll
        for (int i = 0; i < 4; i++) {
            af[i][0] = *(const bf16x8*)(L + ab0 + 16384 + i * 2048);
            af[i][1] = *(const bf16x8*)(L + ab1 + 16384 + i * 2048);
        }
        STAGE2(pAlo0, pAlo1, cur * 32768);  // slot last ds_read in r0, >=2 barriers ago
        BARX();
        __builtin_amdgcn_s_setprio(1);
#pragma unroll
        for (int i = 0; i < 4; i++)
#pragma unroll
            for (int j = 0; j < 2; j++) {
                acc[4 + i][2 + j] = __builtin_amdgcn_mfma_f32_16x16x32_bf16(af[i][0], bhi[j][0], acc[4 + i][2 + j], 0, 0, 0);
                acc[4 + i][2 + j] = __builtin_amdgcn_mfma_f32_16x16x32_bf16(af[i][1], bhi[j][1], acc[4 + i][2 + j], 0, 0, 0);
            }
        __builtin_amdgcn_s_setprio(0);
        BARX();

        // ---- phase r3: quadrant (m-hi, n-lo), regs only; stage B-lo(t+2) ----
        STAGE2(pBlo0, pBlo1, 65536 + cur * 32768);
        __builtin_amdgcn_s_setprio(1);
#pragma unroll
        for (int i = 0; i < 4; i++)
#pragma unroll
            for (int j = 0; j < 2; j++) {
                acc[4 + i][j] = __builtin_amdgcn_mfma_f32_16x16x32_bf16(af[i][0], blo[j][0], acc[4 + i][j], 0, 0, 0);
                acc[4 + i][j] = __builtin_amdgcn_mfma_f32_16x16x32_bf16(af[i][1], blo[j][1], acc[4 + i][j], 0, 0, 0);
            }
        __builtin_amdgcn_s_setprio(0);
        asm volatile("s_waitcnt vmcnt(8)" ::: "memory");  // lo(t+1) landed
        BARX();

        pAlo0 += 64; pAlo1 += 64; pAhi0 += 64; pAhi1 += 64;
        pBlo0 += 64; pBlo1 += 64; pBhi0 += 64; pBhi1 += 64;
    }

    // epilogue
    int seg = (int)(n0 >> 9);        // 0=q 1=k 2=g 3=v
    int nl0 = (int)(n0 & 511);
    const float* bias = seg == 0 ? bq : seg == 1 ? bk : seg == 2 ? bg : bv;

    if (seg == 3 && fl == 0) {
#pragma unroll
        for (int im = 0; im < 8; im++)
#pragma unroll
            for (int jn = 0; jn < 4; jn++) {
                int nl = nl0 + wn * 64 + (jn >> 1) * 32 + (jn & 1) * 16 + ln15;
                float bsv = bias[nl];
                long mb = m0 + wm * 128 + (im >> 2) * 64 + (im & 3) * 16 + q4 * 4;
                unsigned short h0 = f2b(fw(acc[im][jn][0] + bsv));
                unsigned short h1 = f2b(fw(acc[im][jn][1] + bsv));
                unsigned short h2 = f2b(fw(acc[im][jn][2] + bsv));
                unsigned short h3 = f2b(fw(acc[im][jn][3] + bsv));
                uint2 pk;
                pk.x = (unsigned int)h0 | ((unsigned int)h1 << 16);
                pk.y = (unsigned int)h2 | ((unsigned int)h3 << 16);
                *(uint2*)(vT + (long)nl * T_LEN + mb) = pk;
            }
    } else {
#pragma unroll
        for (int im = 0; im < 8; im++)
#pragma unroll
            for (int jn = 0; jn < 4; jn++)
#pragma unroll
                for (int ii = 0; ii < 4; ii++) {
                    int dm = fl ? ln15 : q4 * 4 + ii;
                    int dn = fl ? q4 * 4 + ii : ln15;
                    long m = m0 + wm * 128 + (im >> 2) * 64 + (im & 3) * 16 + dm;
                    int nl = nl0 + wn * 64 + (jn >> 1) * 32 + (jn & 1) * 16 + dn;
                    float v = fw(acc[im][jn][ii] + bias[nl]);
                    if (seg == 1 || seg == 2) v = 1.0f / (1.0f + __expf(-v));
                    if (seg == 0)
                        qb[m * K_DIM + nl] = f2b(v);
                    else if (seg == 1)
                        kb[m * K_DIM + nl] = f2b(v);
                    else if (seg == 2)
                        gb[m * K_DIM + nl] = v;
                    else
                        vT[(long)nl * T_LEN + m] = f2b(v);
                }
    }
}

// ---------------------------------------------------------------------------
// Final projection GEMM, same structure/addressing. A=[T][KT], BT=[N][KT],
// fp32 out + bias. KT runtime (512), power of 2, >= 192.
__global__ __launch_bounds__(512, 2) void gemm256_k(const unsigned short* __restrict__ A,
                                                    const unsigned short* __restrict__ BT,
                                                    const float* __restrict__ bias,
                                                    float* __restrict__ out,
                                                    int N, int KT,
                                                    const int* __restrict__ flagp) {
    __shared__ short lds[65536];
    int fl = *flagp;
    int tid = threadIdx.x;
    int lane = tid & 63;
    int ln15 = lane & 15, q4 = lane >> 4;
    int w = tid >> 6;
    int wm = w >> 2, wn = w & 3;
    long m0 = (long)blockIdx.x * 256, n0 = (long)blockIdx.y * 256;

    unsigned slot = ((unsigned)(q4 * 16)) ^ ((unsigned)((ln15 & 7) << 4));
    unsigned aoff0 = (unsigned)(wm * 8192 + ln15 * 128) + slot;
    unsigned boff0 = 65536u + (unsigned)(wn * 4096 + ln15 * 128) + slot;

    int idx0 = tid, idx1 = 512 + tid;
    int r0_ = idx0 >> 3, r1_ = idx1 >> 3;
    int c80 = (idx0 & 7) ^ (r0_ & 7);
    int c81 = (idx1 & 7) ^ (r1_ & 7);
    int trA0 = ((r0_ >> 6) & 1) * 128 + (r0_ & 63);
    int trA1 = ((r1_ >> 6) & 1) * 128 + (r1_ & 63);
    int tcB0 = ((r0_ >> 5) & 3) * 64 + (r0_ & 31);
    int tcB1 = ((r1_ >> 5) & 3) * 64 + (r1_ & 31);
    const unsigned short* pAlo0 = A + (m0 + trA0) * (long)KT + c80 * 8;
    const unsigned short* pAlo1 = A + (m0 + trA1) * (long)KT + c81 * 8;
    const unsigned short* pAhi0 = pAlo0 + 64 * KT;
    const unsigned short* pAhi1 = pAlo1 + 64 * KT;
    const unsigned short* pBlo0 = BT + (n0 + tcB0) * (long)KT + c80 * 8;
    const unsigned short* pBlo1 = BT + (n0 + tcB1) * (long)KT + c81 * 8;
    const unsigned short* pBhi0 = pBlo0 + 32 * KT;
    const unsigned short* pBhi1 = pBlo1 + 32 * KT;

    f32x4 acc[8][4] = {};

    STAGE2(pAlo0, pAlo1, 0);
    STAGE2(pBlo0, pBlo1, 65536);
    ORDER();
    STAGE2(pBhi0, pBhi1, 65536 + 16384);
    STAGE2(pAhi0, pAhi1, 16384);
    ORDER();
    pAlo0 += 64; pAlo1 += 64; pBlo0 += 64; pBlo1 += 64;
    STAGE2(pAlo0, pAlo1, 32768);
    STAGE2(pBlo0, pBlo1, 65536 + 32768);
    ORDER();
    pAlo0 += 64; pAlo1 += 64; pBlo0 += 64; pBlo1 += 64;
    pAhi0 += 64; pAhi1 += 64; pBhi0 += 64; pBhi1 += 64;
    asm volatile("s_waitcnt vmcnt(8)" ::: "memory");
    BARX();

    int cur = 0;
    const char* L = (const char*)lds;
    for (int kt = 0; kt < KT; kt += 64, cur ^= 1) {
        int nxt = cur ^ 1;
        unsigned bufb = (unsigned)cur << 15;
        unsigned ab0 = aoff0 + bufb, ab1 = ab0 ^ 64u;
        unsigned bb0 = boff0 + bufb, bb1 = bb0 ^ 64u;
        bf16x8 af[4][2], blo[2][2], bhi[2][2];

#pragma unroll
        for (int i = 0; i < 4; i++) {
            af[i][0] = *(const bf16x8*)(L + ab0 + i * 2048);
            af[i][1] = *(const bf16x8*)(L + ab1 + i * 2048);
        }
#pragma unroll
        for (int j = 0; j < 2; j++) {
            blo[j][0] = *(const bf16x8*)(L + bb0 + j * 2048);
            blo[j][1] = *(const bf16x8*)(L + bb1 + j * 2048);
        }
        STAGE2(pBhi0, pBhi1, 65536 + nxt * 32768 + 16384);
        BARX();
        __builtin_amdgcn_s_setprio(1);
#pragma unroll
        for (int i = 0; i < 4; i++)
#pragma unroll
            for (int j = 0; j < 2; j++) {
                acc[i][j] = __builtin_amdgcn_mfma_f32_16x16x32_bf16(af[i][0], blo[j][0], acc[i][j], 0, 0, 0);
                acc[i][j] = __builtin_amdgcn_mfma_f32_16x16x32_bf16(af[i][1], blo[j][1], acc[i][j], 0, 0, 0);
            }
        __builtin_amdgcn_s_setprio(0);
        asm volatile("s_waitcnt vmcnt(8)" ::: "memory");
        BARX();

#pragma unroll
        for (int j = 0; j < 2; j++) {
            bhi[j][0] = *(const bf16x8*)(L + bb0 + 16384 + j * 2048);
            bhi[j][1] = *(const bf16x8*)(L + bb1 + 16384 + j * 2048);
        }
        STAGE2(pAhi0, pAhi1, nxt * 32768 + 16384);
        BARX();
        __builtin_amdgcn_s_setprio(1);
#pragma unroll
        for (int i = 0; i < 4; i++)
#pragma unroll
            for (int j = 0; j < 2; j++) {
                acc[i][2 + j] = __builtin_amdgcn_mfma_f32_16x16x32_bf16(af[i][0], bhi[j][0], acc[i][2 + j], 0, 0, 0);
                acc[i][2 + j] = __builtin_amdgcn_mfma_f32_16x16x32_bf16(af[i][1], bhi[j][1], acc[i][2 + j], 0, 0, 0);
            }
        __builtin_amdgcn_s_setprio(0);
        asm volatile("s_waitcnt vmcnt(8)" ::: "memory");
        BARX();

#pragma unroll
        for (int i = 0; i < 4; i++) {
            af[i][0] = *(const bf16x8*)(L + ab0 + 16384 + i * 2048);
            af[i][1] = *(const bf16x8*)(L + ab1 + 16384 + i * 2048);
        }
        STAGE2(pAlo0, pAlo1, cur * 32768);
        BARX();
        __builtin_amdgcn_s_setprio(1);
#pragma unroll
        for (int i = 0; i < 4; i++)
#pragma unroll
            for (int j = 0; j < 2; j++) {
                acc[4 + i][2 + j] = __builtin_amdgcn_mfma_f32_16x16x32_bf16(af[i][0], bhi[j][0], acc[4 + i][2 + j], 0, 0, 0);
                acc[4 + i][2 + j] = __builtin_amdgcn_mfma_f32_16x16x32_bf16(af[i][1], bhi[j][1], acc[4 + i][2 + j], 0, 0, 0);
            }
        __builtin_amdgcn_s_setprio(0);
        BARX();

        STAGE2(pBlo0, pBlo1, 65536 + cur * 32768);
        __builtin_amdgcn_s_setprio(1);
#pragma unroll
        for (int i = 0; i < 4; i++)
#pragma unroll
            for (int j = 0; j < 2; j++) {
                acc[4 + i][j] = __builtin_amdgcn_mfma_f32_16x16x32_bf16(af[i][0], blo[j][0], acc[4 + i][j], 0, 0, 0);
                acc[4 + i][j] = __builtin_amdgcn_mfma_f32_16x16x32_bf16(af[i][1], blo[j][1], acc[4 + i][j], 0, 0, 0);
            }
        __builtin_amdgcn_s_setprio(0);
        asm volatile("s_waitcnt vmcnt(8)" ::: "memory");
        BARX();

        pAlo0 += 64; pAlo1 += 64; pAhi0 += 64; pAhi1 += 64;
        pBlo0 += 64; pBlo1 += 64; pBhi0 += 64; pBhi1 += 64;
    }

#pragma unroll
    for (int im = 0; im < 8; im++)
#pragma unroll
        for (int jn = 0; jn < 4; jn++)
#pragma unroll
            for (int ii = 0; ii < 4; ii++) {
                int dm = fl ? ln15 : q4 * 4 + ii;
                int dn = fl ? q4 * 4 + ii : ln15;
                long m = m0 + wm * 128 + (im >> 2) * 64 + (im & 3) * 16 + dm;
                long n = n0 + wn * 64 + (jn >> 1) * 32 + (jn & 1) * 16 + dn;
                out[m * N + n] = fw(acc[im][jn][ii] + bias[n]);
            }
}

// ---------------------------------------------------------------------------
// Per (chunk, dim): cumulative gate products. g cached in 64 regs; q->q*P,
// k->k/P in place; khatT routed through a padded LDS tile for coalesced
// 128B-segment writes (was: 64 lanes x 16B scattered across 16KB-strided rows).
__global__ __launch_bounds__(256) void cumprod_k(const float* __restrict__ g,
                                                 unsigned short* __restrict__ q,
                                                 unsigned short* __restrict__ k,
                                                 unsigned short* __restrict__ khatT,
                                                 float* __restrict__ pend) {
    __shared__ unsigned short tile[256][80];  // 80-short pitch: 16B-aligned rows, 2-way banks
    int c = blockIdx.x;
    int half = blockIdx.y;
    int tid = threadIdx.x;
    int d = half * 256 + tid;
    long base = (long)c * CHUNK * K_DIM + d;
    float gv[CHUNK];
#pragma unroll
    for (int s = 0; s < CHUNK; s++) gv[s] = g[base + (long)s * K_DIM];
    float P = 1.0f;
#pragma unroll
    for (int s = 0; s < CHUNK; s++) { P = fmaxf(P * gv[s], 1e-37f); gv[s] = P; }  // gv = cumP
    pend[c * K_DIM + d] = P;
    float Pend = P;
#pragma unroll
    for (int s8 = 0; s8 < CHUNK; s8 += 8) {
        unsigned int packed[4];
#pragma unroll
        for (int u = 0; u < 8; u++) {
            int s = s8 + u;
            long idx = base + (long)s * K_DIM;
            float Pc = gv[s];
            float qv = fw(b2f(q[idx]) * Pc);
            q[idx] = f2b(qv);
            float kv = b2f(k[idx]);
            float kt = kv / Pc;
            kt = fmaxf(fminf(kt, 3e37f), -3e37f);
            k[idx] = f2b(kt);
            float ratio = Pend / Pc;  // in (0,1]
            unsigned short kh = f2b(fw(kv * ratio));
            if (u & 1)
                packed[u >> 1] |= ((unsigned int)kh) << 16;
            else
                packed[u >> 1] = kh;
        }
        uint4 pk;
        pk.x = packed[0]; pk.y = packed[1]; pk.z = packed[2]; pk.w = packed[3];
        *(uint4*)&tile[tid][s8] = pk;
    }
    __syncthreads();
    int wv = tid >> 6, l = tid & 63;
    int colb = (l & 7) * 8;
#pragma unroll
    for (int j = 0; j < 8; j++) {
        int row = wv * 64 + j * 8 + (l >> 3);
        uint4 pk = *(const uint4*)&tile[row][colb];
        *(uint4*)(khatT + (long)(half * 256 + row) * T_LEN + c * CHUNK + colb) = pk;
    }
}

// ---------------------------------------------------------------------------
// Single sequential chunk scan over all NCHUNK chunks, acc starts at 0.
// 4-deep register prefetch of khatT/vT fragments and decay factors.
__global__ __launch_bounds__(256) void scan_k(const unsigned short* __restrict__ khatT,
                                              const unsigned short* __restrict__ vT,
                                              const float* __restrict__ pend,
                                              unsigned short* __restrict__ ST,
                                              float* __restrict__ fstate,
                                              const int* __restrict__ flagp) {
    int fl = *flagp;
    int lane = threadIdx.x & 63, w = threadIdx.x >> 6;
    int ln15 = lane & 15, q4 = lane >> 4;
    int k0 = (blockIdx.x & 15) * 32 + (w & 1) * 16;
    int v0 = (blockIdx.x >> 4) * 32 + (w >> 1) * 16;
    f32x4 acc = {0.f, 0.f, 0.f, 0.f};
    const unsigned short* kb_ = khatT + (long)(k0 + ln15) * T_LEN + q4 * 8;
    const unsigned short* vb_ = vT + (long)(v0 + ln15) * T_LEN + q4 * 8;

    bf16x8 kf0[2], vf0[2], kf1[2], vf1[2], kf2[2], vf2[2], kf3[2], vf3[2];
    float4 pdv[4];
    float pds[4];

#define LOADSET(s, c)                                                        \
    do {                                                                     \
        long off_ = (long)(c) * CHUNK;                                       \
        kf##s[0] = *(const bf16x8*)(kb_ + off_);                             \
        kf##s[1] = *(const bf16x8*)(kb_ + off_ + 32);                        \
        vf##s[0] = *(const bf16x8*)(vb_ + off_);                             \
        vf##s[1] = *(const bf16x8*)(vb_ + off_ + 32);                        \
        if (!fl)                                                             \
            pdv[s] = *(const float4*)(pend + (c) * K_DIM + k0 + q4 * 4);     \
        else                                                                 \
            pds[s] = pend[(c) * K_DIM + k0 + ln15];                          \
    } while (0)

    LOADSET(0, 0); LOADSET(1, 1); LOADSET(2, 2); LOADSET(3, 3);

#define STEP(s, c)                                                                             \
    do {                                                                                       \
        if (!fl) {                                                                             \
            uint2 pk_;                                                                         \
            pk_.x = (unsigned int)f2b(fw(acc[0])) | ((unsigned int)f2b(fw(acc[1])) << 16);     \
            pk_.y = (unsigned int)f2b(fw(acc[2])) | ((unsigned int)f2b(fw(acc[3])) << 16);     \
            *(uint2*)(ST + ((long)(c) * V_DIM + v0 + ln15) * K_DIM + k0 + q4 * 4) = pk_;       \
            acc[0] *= pdv[s].x; acc[1] *= pdv[s].y; acc[2] *= pdv[s].z; acc[3] *= pdv[s].w;    \
        } else {                                                                               \
            ST[((long)(c) * V_DIM + v0 + q4 * 4 + 0) * K_DIM + k0 + ln15] = f2b(fw(acc[0]));   \
            ST[((long)(c) * V_DIM + v0 + q4 * 4 + 1) * K_DIM + k0 + ln15] = f2b(fw(acc[1]));   \
            ST[((long)(c) * V_DIM + v0 + q4 * 4 + 2) * K_DIM + k0 + ln15] = f2b(fw(acc[2]));   \
            ST[((long)(c) * V_DIM + v0 + q4 * 4 + 3) * K_DIM + k0 + ln15] = f2b(fw(acc[3]));   \
            acc[0] *= pds[s]; acc[1] *= pds[s]; acc[2] *= pds[s]; acc[3] *= pds[s];            \
        }                                                                                      \
        acc = __builtin_amdgcn_mfma_f32_16x16x32_bf16(kf##s[0], vf##s[0], acc, 0, 0, 0);       \
        acc = __builtin_amdgcn_mfma_f32_16x16x32_bf16(kf##s[1], vf##s[1], acc, 0, 0, 0);       \
        int cp_ = (c) + 4;                                                                     \
        if (cp_ > NCHUNK - 1) cp_ = NCHUNK - 1;                                                \
        LOADSET(s, cp_);                                                                       \
    } while (0)

    for (int c = 0; c < NCHUNK; c += 4) {
        STEP(0, c);
        STEP(1, c + 1);
        STEP(2, c + 2);
        STEP(3, c + 3);
    }
#undef STEP
#undef LOADSET

#pragma unroll
    for (int i = 0; i < 4; i++) {
        int dk = fl ? ln15 : q4 * 4 + i;
        int dv = fl ? q4 * 4 + i : ln15;
        fstate[(long)(k0 + dk) * V_DIM + v0 + dv] = fw(acc[i]);
    }
}

// ---------------------------------------------------------------------------
// Per-chunk output: outs = Qs @ S_c + tril(Qs @ Ks^T) @ V_c. grid 2*NCHUNK.
__global__ __launch_bounds__(256) void intra_k(const unsigned short* __restrict__ qs,
                                               const unsigned short* __restrict__ ks,
                                               const unsigned short* __restrict__ vT,
                                               const unsigned short* __restrict__ ST,
                                               unsigned short* __restrict__ outs,
                                               const int* __restrict__ flagp) {
    __shared__ unsigned short Ab[64 * 72];
    int fl = *flagp;
    long cloc = blockIdx.x >> 1;
    int c = (int)cloc, h = blockIdx.x & 1;
    int lane = threadIdx.x & 63, w = threadIdx.x >> 6;
    int ln15 = lane & 15, q4 = lane >> 4;
    long t0 = (long)c * CHUNK;

    // Stage A: A = Qs @ Ks^T (64x64), causal mask (s <= t), bf16 into LDS
    {
        f32x4 accA[4] = {};
        for (int kk = 0; kk < K_DIM; kk += 32) {
            bf16x8 a = *(const bf16x8*)(qs + (t0 + 16 * w + ln15) * K_DIM + kk + q4 * 8);
#pragma unroll
            for (int j = 0; j < 4; j++) {
                bf16x8 b = *(const bf16x8*)(ks + (t0 + 16 * j + ln15) * K_DIM + kk + q4 * 8);
                accA[j] = __builtin_amdgcn_mfma_f32_16x16x32_bf16(a, b, accA[j], 0, 0, 0);
            }
        }
#pragma unroll
        for (int j = 0; j < 4; j++)
#pragma unroll
            for (int i = 0; i < 4; i++) {
                int dt = fl ? ln15 : q4 * 4 + i;
                int ds = fl ? q4 * 4 + i : ln15;
                int tl = 16 * w + dt;
                int s = 16 * j + ds;
                float av = (s <= tl) ? accA[j][i] : 0.0f;
                Ab[tl * 72 + s] = f2b(fw(av));
            }
    }
    __syncthreads();

    // Stage B: wave handles 64 v-cols. acc = Qs @ S^T + Ab @ V
    int v0 = h * 256 + w * 64;
    f32x4 acc[4][4] = {};
    for (int kk = 0; kk < K_DIM; kk += 32) {
        bf16x8 a[4], b[4];
#pragma unroll
        for (int i = 0; i < 4; i++)
            a[i] = *(const bf16x8*)(qs + (t0 + 16 * i + ln15) * K_DIM + kk + q4 * 8);
#pragma unroll
        for (int j = 0; j < 4; j++)
            b[j] = *(const bf16x8*)(ST + (cloc * V_DIM + v0 + 16 * j + ln15) * K_DIM + kk + q4 * 8);
#pragma unroll
        for (int i = 0; i < 4; i++)
#pragma unroll
            for (int j = 0; j < 4; j++)
                acc[i][j] = __builtin_amdgcn_mfma_f32_16x16x32_bf16(a[i], b[j], acc[i][j], 0, 0, 0);
    }
#pragma unroll
    for (int s0 = 0; s0 < CHUNK; s0 += 32) {
        bf16x8 a[4], b[4];
#pragma unroll
        for (int i = 0; i < 4; i++)
            a[i] = *(const bf16x8*)(Ab + (16 * i + ln15) * 72 + s0 + q4 * 8);
#pragma unroll
        for (int j = 0; j < 4; j++)
            b[j] = *(const bf16x8*)(vT + (long)(v0 + 16 * j + ln15) * T_LEN + t0 + s0 + q4 * 8);
#pragma unroll
        for (int i = 0; i < 4; i++)
#pragma unroll
            for (int j = 0; j < 4; j++)
                acc[i][j] = __builtin_amdgcn_mfma_f32_16x16x32_bf16(a[i], b[j], acc[i][j], 0, 0, 0);
    }
#pragma unroll
    for (int i = 0; i < 4; i++)
#pragma unroll
        for (int j = 0; j < 4; j++)
#pragma unroll
            for (int ii = 0; ii < 4; ii++) {
                int dt = fl ? ln15 : q4 * 4 + ii;
                int dv = fl ? q4 * 4 + ii : ln15;
                outs[(t0 + 16 * i + dt) * V_DIM + v0 + 16 * j + dv] = f2b(fw(acc[i][j][ii]));
            }
}

// ---------------------------------------------------------------------------
extern "C" void kernel_launch(void* const* d_in, const int* in_sizes, int n_in,
                              void* d_out, int out_size, void* d_ws, size_t ws_size,
                              hipStream_t stream) {
    const float* hs = (const float*)d_in[0];
    const float* Wq = (const float*)d_in[1];
    const float* bq = (const float*)d_in[2];
    const float* Wk = (const float*)d_in[3];
    const float* bk = (const float*)d_in[4];
    const float* Wv = (const float*)d_in[5];
    const float* bv = (const float*)d_in[6];
    const float* Wg = (const float*)d_in[7];
    const float* bg = (const float*)d_in[8];
    const float* Wo = (const float*)d_in[9];
    const float* bo = (const float*)d_in[10];

    float* out = (float*)d_out;  // fp32 output

    // Workspace layout, peak 109 MB (<= 116 MB demonstrated safe).
    // Liveness: WT [prep,proj] / outsb [intra,gemm] share 0..8.
    //           gb [proj,cumprod] + hsb [prep,proj] dead before scan,
    //           so STb (64 MB, [scan,intra]) reuses 44..108.
    //           Tail prefetch overruns (proj/gemm) stay inside mapped ws.
    char* ws = (char*)d_ws;
    const size_t MB = 1024 * 1024;
    unsigned short* WT = (unsigned short*)(ws + 0 * MB);      // 8 MB: q|k|g|v transposed
    unsigned short* outsb = (unsigned short*)(ws + 0 * MB);   // 8 MB (after proj)
    unsigned short* WoT = (unsigned short*)(ws + 8 * MB);     // 2 MB
    unsigned short* qb = (unsigned short*)(ws + 10 * MB);     // 8 MB
    unsigned short* kb = (unsigned short*)(ws + 18 * MB);     // 8 MB
    unsigned short* vTb = (unsigned short*)(ws + 26 * MB);    // 8 MB
    unsigned short* khatT = (unsigned short*)(ws + 34 * MB);  // 8 MB
    float* pend = (float*)(ws + 42 * MB);                     // 256 KB
    int* flags = (int*)(ws + 42 * MB + 256 * 1024);           // [0] layout flag
    float* gb = (float*)(ws + 44 * MB);                       // 16 MB fp32 (dead after cumprod)
    unsigned short* STb = (unsigned short*)(ws + 44 * MB);    // 64 MB (all 128 chunks)
    unsigned short* hsb = (unsigned short*)(ws + 60 * MB);    // 33.6 MB (dead after proj)
    float* fsspare = (float*)(ws + 108 * MB);                 // 1 MB -> peak 109 MB
    (void)ws_size; (void)in_sizes; (void)n_in;

    float* finalst =
        ((long)out_size >= (long)T_LEN * O_DIM + (long)K_DIM * V_DIM)
            ? out + (long)T_LEN * O_DIM
            : fsspare;

    dim3 b256(256);
    hipMemsetAsync(flags, 0, 16, stream);
    probe_k<<<dim3(1), dim3(64), 0, stream>>>(flags);
    // conv + all weight transposes, one launch
    prep_k<<<dim3(8192 + 5 * 1024), b256, 0, stream>>>(hs, hsb, Wq, Wk, Wg, Wv, Wo, WT, WoT);
    // fused q/k/g/v projection (v written transposed), 256x256 8-phase
    proj_gemm256_k<<<dim3(T_LEN / 256, 8), dim3(512), 0, stream>>>(
        hsb, WT, bq, bk, bg, bv, qb, kb, gb, vTb, flags);
    // gate cumulative products
    cumprod_k<<<dim3(NCHUNK, K_DIM / 256), b256, 0, stream>>>(gb, qb, kb, khatT, pend);
    // single-pass chunk scan (writes all 128 chunk states + final state)
    scan_k<<<dim3(256), b256, 0, stream>>>(khatT, vTb, pend, STb, finalst, flags);
    // intra-chunk outputs, full GPU in one launch
    intra_k<<<dim3(2 * NCHUNK), b256, 0, stream>>>(qb, kb, vTb, STb, outsb, flags);
    // final projection -> fp32 d_out, 256x256 8-phase
    gemm256_k<<<dim3(T_LEN / 256, O_DIM / 256), dim3(512), 0, stream>>>(
        outsb, WoT, bo, out, O_DIM, V_DIM, flags);
}